// Round 1
// baseline (781.628 us; speedup 1.0000x reference)
//
#include <hip/hip_runtime.h>

#define NB 8
#define NN 25200
#define NCLS 80
#define NSTR 85
#define MAXDET 300
#define NSEG 394           // ceil(25200/64)
#define NPAD (NSEG * 64)   // 25216
#define CONF_T 0.4f
#define IOU_T 0.45f
#define MAX_WH_C 4096.0f

// ---------------- Kernel 1: per-candidate score / class ----------------
__global__ __launch_bounds__(256) void prep_kernel(const float* __restrict__ pred,
                                                   float* __restrict__ score_ws,
                                                   int* __restrict__ cls_ws) {
    int g = blockIdx.x * blockDim.x + threadIdx.x;
    if (g >= NB * NN) return;
    const float* p = pred + (size_t)g * NSTR;
    float obj = p[4];
    float best = p[5] * obj;
    int bc = 0;
#pragma unroll 8
    for (int j = 1; j < NCLS; ++j) {
        float s = p[5 + j] * obj;
        if (s > best) { best = s; bc = j; }   // strict > : first-index argmax like jnp
    }
    bool valid = (obj > CONF_T) && (best > CONF_T);
    score_ws[g] = valid ? best : -1.0f;
    cls_ws[g] = bc;
}

// ---------------- Kernel 2: per-image lazy greedy NMS ----------------
__global__ __launch_bounds__(1024) void nms_kernel(const float* __restrict__ pred,
                                                   const float* __restrict__ logits,
                                                   const float* __restrict__ score_ws,
                                                   const int* __restrict__ cls_ws,
                                                   float* __restrict__ out,
                                                   int use_ws) {
#pragma clang fp contract(off)
    __shared__ float s_score[NPAD];
    __shared__ float s_segmax[NSEG];
    __shared__ float s_kobox[MAXDET][4];
    __shared__ float s_karea[MAXDET];
    __shared__ int   s_kidx[MAXDET];
    __shared__ float s_kscore[MAXDET];
    __shared__ float s_kcls[MAXDET];
    __shared__ int   s_kc;

    const int b = blockIdx.x;
    const int tid = threadIdx.x;
    const int lane = tid & 63;
    const int wid = tid >> 6;
    const float* predb = pred + (size_t)b * NN * NSTR;
    const float* logb  = logits + (size_t)b * NN * NCLS;

    // ---- Phase A: scores into LDS ----
    if (use_ws) {
        const float* sb = score_ws + (size_t)b * NN;
        for (int i = tid; i < NN; i += 1024) s_score[i] = sb[i];
    } else {
        for (int i = tid; i < NN; i += 1024) {
            const float* p = predb + (size_t)i * NSTR;
            float obj = p[4];
            float best = p[5] * obj;
            for (int j = 1; j < NCLS; ++j) {
                float s = p[5 + j] * obj;
                if (s > best) best = s;
            }
            bool valid = (obj > CONF_T) && (best > CONF_T);
            s_score[i] = valid ? best : -1.0f;
        }
    }
    for (int i = NN + tid; i < NPAD; i += 1024) s_score[i] = -1.0f;
    __syncthreads();

    // segment maxima (wave-parallel)
    for (int s = wid; s < NSEG; s += 16) {
        float v = s_score[(s << 6) + lane];
        for (int m = 32; m >= 1; m >>= 1) {
            float ov = __shfl_xor(v, m);
            v = ov > v ? ov : v;
        }
        if (lane == 0) s_segmax[s] = v;
    }
    __syncthreads();

    // ---- Phase B: single-wave serial pop + backward IoU check ----
    if (wid == 0) {
        int kc = 0;
        while (kc < MAXDET) {
            // argmax over segment maxima (tie -> lowest segment)
            float bv = -2.0f; int bs = 0;
            for (int s = lane; s < NSEG; s += 64) {
                float v = s_segmax[s];
                if (v > bv) { bv = v; bs = s; }
            }
            for (int m = 32; m >= 1; m >>= 1) {
                float ov = __shfl_xor(bv, m);
                int   os = __shfl_xor(bs, m);
                if (ov > bv || (ov == bv && os < bs)) { bv = ov; bs = os; }
            }
            if (bv <= 0.0f) break;   // exhausted -> remaining steps all keep=False

            // drill into winning segment (tie -> lowest element index)
            int base = bs << 6;
            float v = s_score[base + lane];
            float dv = v; int dl = lane;
            for (int m = 32; m >= 1; m >>= 1) {
                float ov = __shfl_xor(dv, m);
                int   ol = __shfl_xor(dl, m);
                if (ov > dv || (ov == dv && ol < dl)) { dv = ov; dl = ol; }
            }
            int widx = base + dl;

            // fetch candidate xywh early (uniform address -> broadcast load)
            const float* pp = predb + (size_t)widx * NSTR;
            float cx = pp[0], cy = pp[1], w = pp[2], h = pp[3];

            // remove candidate, recompute this segment's max
            float v2 = (lane == dl) ? -1.0f : v;
            for (int m = 32; m >= 1; m >>= 1) {
                float ov = __shfl_xor(v2, m);
                v2 = ov > v2 ? ov : v2;
            }
            if (lane == 0) { s_score[widx] = -1.0f; s_segmax[bs] = v2; }

            // candidate class
            float clsf;
            if (use_ws) {
                clsf = (float)cls_ws[(size_t)b * NN + widx];
            } else {
                float obj = pp[4];
                float v1 = pp[5 + lane] * obj; int j1 = lane;
                if (lane < 16) {
                    float va = pp[69 + lane] * obj;
                    if (va > v1) { v1 = va; j1 = lane + 64; }
                }
                for (int m = 32; m >= 1; m >>= 1) {
                    float ov = __shfl_xor(v1, m);
                    int   oj = __shfl_xor(j1, m);
                    if (ov > v1 || (ov == v1 && oj < j1)) { v1 = ov; j1 = oj; }
                }
                clsf = (float)j1;
            }

            // candidate class-offset box (replicating reference op order)
            float off = clsf * MAX_WH_C;
            float x1 = (cx - w * 0.5f) + off;
            float y1 = (cy - h * 0.5f) + off;
            float x2 = (cx + w * 0.5f) + off;
            float y2 = (cy + h * 0.5f) + off;
            float area = (x2 - x1) * (y2 - y1);

            // backward check vs kept list
            bool sup = false;
            for (int t = lane; t < kc; t += 64) {
                float lx = fmaxf(s_kobox[t][0], x1);
                float ly = fmaxf(s_kobox[t][1], y1);
                float rx = fminf(s_kobox[t][2], x2);
                float ry = fminf(s_kobox[t][3], y2);
                float iw = fmaxf(rx - lx, 0.0f);
                float ih = fmaxf(ry - ly, 0.0f);
                float inter = iw * ih;
                float iou = inter / (s_karea[t] + area - inter + 1e-9f);
                if (iou > IOU_T) sup = true;
            }
            sup = (bool)__any((int)sup);
            if (!sup) {
                if (lane == 0) {
                    s_kobox[kc][0] = x1; s_kobox[kc][1] = y1;
                    s_kobox[kc][2] = x2; s_kobox[kc][3] = y2;
                    s_karea[kc] = area; s_kidx[kc] = widx;
                    s_kscore[kc] = bv;  s_kcls[kc] = clsf;
                }
                kc++;
            }
        }
        if (lane == 0) s_kc = kc;
    }
    __syncthreads();

    // ---- Phase C: outputs (every element written every launch) ----
    int kc = s_kc;
    if (tid < MAXDET) {
        int t = tid;
        float o0 = 0, o1 = 0, o2 = 0, o3 = 0, o4 = 0, o5 = 0;
        if (t < kc) {
            int idx = s_kidx[t];
            const float* pp = predb + (size_t)idx * NSTR;
            float cx = pp[0], cy = pp[1], w = pp[2], h = pp[3];
            o0 = cx - w * 0.5f; o1 = cy - h * 0.5f;
            o2 = cx + w * 0.5f; o3 = cy + h * 0.5f;
            o4 = s_kscore[t];   o5 = s_kcls[t];
        }
        float* dd = out + (size_t)b * (MAXDET * 6) + (size_t)t * 6;
        dd[0] = o0; dd[1] = o1; dd[2] = o2; dd[3] = o3; dd[4] = o4; dd[5] = o5;
        out[(size_t)NB * MAXDET * 6 + (size_t)NB * MAXDET * NCLS + (size_t)b * MAXDET + t] =
            (t < kc) ? 1.0f : 0.0f;
    }
    float* lbase = out + (size_t)NB * MAXDET * 6 + (size_t)b * (MAXDET * NCLS);
    for (int t = wid; t < MAXDET; t += 16) {
        float* dst = lbase + (size_t)t * NCLS;
        if (t < kc) {
            const float* src = logb + (size_t)s_kidx[t] * NCLS;
            for (int c = lane; c < NCLS; c += 64) dst[c] = src[c];
        } else {
            for (int c = lane; c < NCLS; c += 64) dst[c] = 0.0f;
        }
    }
}

extern "C" void kernel_launch(void* const* d_in, const int* in_sizes, int n_in,
                              void* d_out, int out_size, void* d_ws, size_t ws_size,
                              hipStream_t stream) {
    const float* pred   = (const float*)d_in[0];
    const float* logits = (const float*)d_in[1];
    float* out = (float*)d_out;

    size_t need = (size_t)NB * NN * 4 * 2;   // scores f32 + cls i32
    int use_ws = (d_ws != nullptr && ws_size >= need) ? 1 : 0;
    float* score_ws = (float*)d_ws;
    int*   cls_ws   = (int*)((char*)d_ws + (size_t)NB * NN * 4);

    if (use_ws) {
        int total = NB * NN;
        prep_kernel<<<(total + 255) / 256, 256, 0, stream>>>(pred, score_ws, cls_ws);
    }
    nms_kernel<<<NB, 1024, 0, stream>>>(pred, logits, score_ws, cls_ws, out, use_ws);
}

// Round 2
// 149.067 us; speedup vs baseline: 5.2435x; 5.2435x over previous
//
#include <hip/hip_runtime.h>

#pragma clang fp contract(off)

#define NB 8
#define NN 25200
#define NCLS 80
#define NSTR 85
#define MAXDET 300
#define CONF_T 0.4f
#define IOU_T 0.45f
#define MAX_WH_C 4096.0f

#define SORTN 2048
#define NBIN 1024
#define BINSHIFT 14
#define BINBASE 0x3EC00000u   // bits of 0.375 < bits of any valid score (>0.4)

// ---------------- helpers ----------------
__device__ __forceinline__ float cand_score(const float* __restrict__ p) {
    float obj = p[4];
    float best = p[5] * obj;
    for (int j = 1; j < NCLS; ++j) {
        float s = p[5 + j] * obj;
        if (s > best) best = s;
    }
    return ((obj > CONF_T) && (best > CONF_T)) ? best : -1.0f;
}
__device__ __forceinline__ int cand_cls(const float* __restrict__ p) {
    float obj = p[4];
    float best = p[5] * obj; int bc = 0;
    for (int j = 1; j < NCLS; ++j) {
        float s = p[5 + j] * obj;
        if (s > best) { best = s; bc = j; }   // strict > : first-index argmax
    }
    return bc;
}
__device__ __forceinline__ bool iou_gt(float ax1, float ay1, float ax2, float ay2, float aarea,
                                       float bx1, float by1, float bx2, float by2, float barea) {
    float lx = fmaxf(ax1, bx1);
    float ly = fmaxf(ay1, by1);
    float rx = fminf(ax2, bx2);
    float ry = fminf(ay2, by2);
    float iw = fmaxf(rx - lx, 0.0f);
    float ih = fmaxf(ry - ly, 0.0f);
    float inter = iw * ih;
    float iou = inter / ((aarea + barea - inter) + 1e-9f);
    return iou > IOU_T;
}

// ---------------- Kernel 1: per-candidate score / class ----------------
__global__ __launch_bounds__(256) void prep_kernel(const float* __restrict__ pred,
                                                   float* __restrict__ score_ws,
                                                   int* __restrict__ cls_ws) {
    int g = blockIdx.x * blockDim.x + threadIdx.x;
    if (g >= NB * NN) return;
    const float* p = pred + (size_t)g * NSTR;
    float obj = p[4];
    float best = p[5] * obj;
    int bc = 0;
#pragma unroll 8
    for (int j = 1; j < NCLS; ++j) {
        float s = p[5 + j] * obj;
        if (s > best) { best = s; bc = j; }
    }
    bool valid = (obj > CONF_T) && (best > CONF_T);
    score_ws[g] = valid ? best : -1.0f;
    cls_ws[g] = bc;
}

// ---------------- Kernel 2: sort-then-scan greedy NMS (one block / image) ----------------
__global__ __launch_bounds__(1024) void nms_kernel(const float* __restrict__ pred,
                                                   const float* __restrict__ logits,
                                                   const float* __restrict__ score_ws,
                                                   const int* __restrict__ cls_ws,
                                                   float* __restrict__ out,
                                                   int use_ws) {
    __shared__ unsigned long long s_keys[SORTN];
    __shared__ float sel_x1[SORTN], sel_y1[SORTN], sel_x2[SORTN], sel_y2[SORTN];
    __shared__ float sel_area[SORTN], sel_cls[SORTN];
    __shared__ int   sel_idx[SORTN];
    __shared__ float kx1[MAXDET], ky1[MAXDET], kx2[MAXDET], ky2[MAXDET], karea[MAXDET];
    __shared__ float kscore[MAXDET], kcls[MAXDET];
    __shared__ int   kidx[MAXDET];
    __shared__ int   s_hist[NBIN];
    __shared__ int   s_suppk[64];
    __shared__ unsigned int s_supmask[64][2];
    __shared__ int   s_kc, s_T, s_cnt;

    const int b = blockIdx.x;
    const int tid = threadIdx.x;
    const int lane = tid & 63;
    const int wid = tid >> 6;
    const float* predb = pred + (size_t)b * NN * NSTR;
    const float* logb  = logits + (size_t)b * NN * NCLS;
    const float* sb = score_ws + (size_t)b * NN;
    const int*   cb = cls_ws + (size_t)b * NN;

    int kc_total = 0;
    int prevT = NBIN;

    // ================= selection rounds =================
    while (kc_total < MAXDET && prevT > 0) {
        // ---- histogram of unprocessed bins ----
        s_hist[tid] = 0;
        if (tid == 0) { s_cnt = 0; s_T = NBIN; }
        __syncthreads();
        for (int i = tid; i < NN; i += 1024) {
            float s = use_ws ? sb[i] : cand_score(predb + (size_t)i * NSTR);
            if (s > 0.0f) {
                int bin = (int)((__float_as_uint(s) - BINBASE) >> BINSHIFT);
                if (bin < prevT) atomicAdd(&s_hist[bin], 1);
            }
        }
        __syncthreads();
        // ---- suffix scan (counts in bins >= b) ----
        for (int d = 1; d < NBIN; d <<= 1) {
            int v = s_hist[tid] + ((tid + d < NBIN) ? s_hist[tid + d] : 0);
            __syncthreads();
            s_hist[tid] = v;
            __syncthreads();
        }
        if (s_hist[tid] <= SORTN) atomicMin(&s_T, tid);
        __syncthreads();
        int T = s_T;
        int rem_total = s_hist[0];
        if (T >= prevT) {
            if (rem_total == 0) { prevT = 0; break; }   // exhausted
            T = prevT - 1;                              // pathological huge bin: truncate
        }
        __syncthreads();
        // ---- collect (key = score_bits:~idx for desc score, asc idx) ----
        for (int i = tid; i < NN; i += 1024) {
            float s = use_ws ? sb[i] : cand_score(predb + (size_t)i * NSTR);
            if (s > 0.0f) {
                int bin = (int)((__float_as_uint(s) - BINBASE) >> BINSHIFT);
                if (bin >= T && bin < prevT) {
                    int pos = atomicAdd(&s_cnt, 1);
                    if (pos < SORTN)
                        s_keys[pos] = ((unsigned long long)__float_as_uint(s) << 32)
                                      | (unsigned int)(0xFFFFFFFFu - (unsigned int)i);
                }
            }
        }
        __syncthreads();
        int cnt = s_cnt; if (cnt > SORTN) cnt = SORTN;
        int npow = 64; while (npow < cnt) npow <<= 1;
        for (int i = cnt + tid; i < npow; i += 1024) s_keys[i] = 0ull;
        __syncthreads();
        // ---- bitonic sort descending over npow ----
        for (int k = 2; k <= npow; k <<= 1) {
            for (int j = k >> 1; j > 0; j >>= 1) {
                for (int idx = tid; idx < npow; idx += 1024) {
                    int p = idx ^ j;
                    if (p > idx) {
                        unsigned long long a = s_keys[idx], c = s_keys[p];
                        bool desc = ((idx & k) == 0);
                        if (desc ? (a < c) : (a > c)) { s_keys[idx] = c; s_keys[p] = a; }
                    }
                }
                __syncthreads();
            }
        }
        // ---- precompute offset boxes for selected ----
        for (int t = tid; t < cnt; t += 1024) {
            unsigned long long key = s_keys[t];
            int i = (int)(0xFFFFFFFFu - (unsigned int)(key & 0xFFFFFFFFull));
            const float* p = predb + (size_t)i * NSTR;
            float cx = p[0], cy = p[1], w = p[2], h = p[3];
            int c = use_ws ? cb[i] : cand_cls(p);
            float off = (float)c * MAX_WH_C;
            float x1 = (cx - w * 0.5f) + off;
            float y1 = (cy - h * 0.5f) + off;
            float x2 = (cx + w * 0.5f) + off;
            float y2 = (cy + h * 0.5f) + off;
            sel_x1[t] = x1; sel_y1[t] = y1; sel_x2[t] = x2; sel_y2[t] = y2;
            sel_area[t] = (x2 - x1) * (y2 - y1);
            sel_cls[t] = (float)c;
            sel_idx[t] = i;
        }
        __syncthreads();
        // ---- batched scan: 64 candidates / batch ----
        int nb = (cnt + 63) >> 6;
        for (int batch = 0; batch < nb; ++batch) {
            int kcb = kc_total;
            if (kcb >= MAXDET) break;
            if (tid < 64) { s_suppk[tid] = 0; s_supmask[tid][0] = 0u; s_supmask[tid][1] = 0u; }
            __syncthreads();

            int cloc = tid >> 4, ch = tid & 15;
            int gi = batch * 64 + cloc;
            bool validc = gi < cnt;
            float ax1 = 0, ay1 = 0, ax2 = 0, ay2 = 0, aar = 0;
            if (validc) {
                ax1 = sel_x1[gi]; ay1 = sel_y1[gi];
                ax2 = sel_x2[gi]; ay2 = sel_y2[gi]; aar = sel_area[gi];
            }
            // vs-kept check (16 threads per candidate)
            bool flag = false;
            if (validc) {
                for (int t = ch; t < kcb; t += 16) {
                    if (iou_gt(kx1[t], ky1[t], kx2[t], ky2[t], karea[t],
                               ax1, ay1, ax2, ay2, aar)) flag = true;
                }
            }
            unsigned long long bal = __ballot((int)flag);
            if ((lane & 15) == 0) {
                unsigned int sub = (unsigned int)((bal >> (lane & 48)) & 0xFFFFull);
                s_suppk[cloc] = (sub != 0u);
            }
            // in-batch pairwise masks: candidate cloc vs j in [4*ch, 4*ch+4)
            unsigned int mbits = 0;
            if (validc) {
                for (int jj = 0; jj < 4; ++jj) {
                    int j = (ch << 2) + jj;
                    int gj = batch * 64 + j;
                    if (j > cloc && gj < cnt) {
                        if (iou_gt(ax1, ay1, ax2, ay2, aar,
                                   sel_x1[gj], sel_y1[gj], sel_x2[gj], sel_y2[gj], sel_area[gj]))
                            mbits |= 1u << (j & 31);
                    }
                }
            }
            if (mbits) atomicOr(&s_supmask[cloc][(ch >> 3) & 1], mbits);
            __syncthreads();

            // serial greedy resolution on wave 0
            if (wid == 0) {
                unsigned long long mask =
                    ((unsigned long long)s_supmask[lane][1] << 32) | s_supmask[lane][0];
                bool validj = (batch * 64 + lane) < cnt;
                unsigned long long rem = __ballot((int)(validj && (s_suppk[lane] == 0)));
                unsigned long long keepbits = 0;
                int kcount = kcb;
                while (rem && kcount < MAXDET) {
                    int i = __builtin_ctzll(rem);
                    rem &= rem - 1;
                    keepbits |= 1ull << i;
                    ++kcount;
                    unsigned long long mi = __shfl(mask, i);
                    rem &= ~mi;
                }
                if ((keepbits >> lane) & 1ull) {
                    int pos = kcb + __popcll(keepbits & ((1ull << lane) - 1ull));
                    int g2 = batch * 64 + lane;
                    kx1[pos] = sel_x1[g2]; ky1[pos] = sel_y1[g2];
                    kx2[pos] = sel_x2[g2]; ky2[pos] = sel_y2[g2];
                    karea[pos] = sel_area[g2];
                    kcls[pos] = sel_cls[g2]; kidx[pos] = sel_idx[g2];
                    kscore[pos] = __uint_as_float((unsigned int)(s_keys[g2] >> 32));
                }
                if (lane == 0) s_kc = kcount;
            }
            __syncthreads();
            kc_total = s_kc;
            __syncthreads();
        }
        prevT = T;
    }

    // ================= outputs (every element written every launch) =================
    __syncthreads();
    int kc = kc_total;
    if (tid < MAXDET) {
        int t = tid;
        float o0 = 0, o1 = 0, o2 = 0, o3 = 0, o4 = 0, o5 = 0;
        if (t < kc) {
            int idx = kidx[t];
            const float* pp = predb + (size_t)idx * NSTR;
            float cx = pp[0], cy = pp[1], w = pp[2], h = pp[3];
            o0 = cx - w * 0.5f; o1 = cy - h * 0.5f;
            o2 = cx + w * 0.5f; o3 = cy + h * 0.5f;
            o4 = kscore[t];     o5 = kcls[t];
        }
        float* dd = out + (size_t)b * (MAXDET * 6) + (size_t)t * 6;
        dd[0] = o0; dd[1] = o1; dd[2] = o2; dd[3] = o3; dd[4] = o4; dd[5] = o5;
        out[(size_t)NB * MAXDET * 6 + (size_t)NB * MAXDET * NCLS + (size_t)b * MAXDET + t] =
            (t < kc) ? 1.0f : 0.0f;
    }
    float* lbase = out + (size_t)NB * MAXDET * 6 + (size_t)b * (MAXDET * NCLS);
    for (int t = wid; t < MAXDET; t += 16) {
        float* dst = lbase + (size_t)t * NCLS;
        if (t < kc) {
            const float* src = logb + (size_t)kidx[t] * NCLS;
            for (int c = lane; c < NCLS; c += 64) dst[c] = src[c];
        } else {
            for (int c = lane; c < NCLS; c += 64) dst[c] = 0.0f;
        }
    }
}

extern "C" void kernel_launch(void* const* d_in, const int* in_sizes, int n_in,
                              void* d_out, int out_size, void* d_ws, size_t ws_size,
                              hipStream_t stream) {
    const float* pred   = (const float*)d_in[0];
    const float* logits = (const float*)d_in[1];
    float* out = (float*)d_out;

    size_t need = (size_t)NB * NN * 4 * 2;   // scores f32 + cls i32
    int use_ws = (d_ws != nullptr && ws_size >= need) ? 1 : 0;
    float* score_ws = (float*)d_ws;
    int*   cls_ws   = (int*)((char*)d_ws + (size_t)NB * NN * 4);

    if (use_ws) {
        int total = NB * NN;
        prep_kernel<<<(total + 255) / 256, 256, 0, stream>>>(pred, score_ws, cls_ws);
    }
    nms_kernel<<<NB, 1024, 0, stream>>>(pred, logits, score_ws, cls_ws, out, use_ws);
}